// Round 1
// baseline (90.483 us; speedup 1.0000x reference)
//
#include <hip/hip_runtime.h>

// ---- problem constants ----
#define NCAM      6
#define NB        4
#define NROWS     24          // NB*NCAM
#define NQ        65536       // 256*256
#define MAXLEN_   65536

// flat f32 offsets into d_out (return order)
#define OFF_QGRID   0
#define OFF_RESTORE 3145728    // 24*65536*2
#define OFF_REFPTS  6291456    // + 4*6*256*256*2
#define OFF_COUNTS  18874368   // + 24*65536*4*2

// z values of the 4 pillar points, f32-linspace path
__device__ __forceinline__ float zval(int d) {
    const float z[4] = { -4.5f, -2.16666674613952637f,
                          0.166666507720947266f, 2.5f };
    return z[d];
}

__device__ __forceinline__ float clip21(float x) {
    return fminf(fmaxf(x, -2.1f), 2.1f);
}

// Projection: visibility via multiply-form (sign-exact vs division), stored
// u,v via v_rcp. Bit-identical to the previously passing versions.
__device__ __forceinline__ bool proj_point(const float m[12], float x, float y, float z,
                                           float& u, float& v) {
    float c0 = ((m[0]*x + m[1]*y) + m[2]*z) + m[3];
    float c1 = ((m[4]*x + m[5]*y) + m[6]*z) + m[7];
    float c2 = ((m[8]*x + m[9]*y) + m[10]*z) + m[11];
    float zcl = fmaxf(c2, 1e-5f);
    float inv = __builtin_amdgcn_rcpf(zcl);
    u = (c0 * inv) * (1.0f / 928.0f);   // IMW
    v = (c1 * inv) * (1.0f / 512.0f);   // IMH
    return (c2 > 1e-5f) & (c1 > 0.0f) & (c1 < 512.0f * zcl)
         & (c0 > 0.0f) & (c0 < 928.0f * zcl);
}

__device__ __forceinline__ void load_mat(const float* __restrict__ ego2img, int row, float m[12]) {
    const float* M = ego2img + row * 16;
    #pragma unroll
    for (int i = 0; i < 12; ++i) m[i] = M[i];
}

__device__ __forceinline__ void bev_xy(int qx, int qy, float& x, float& y) {
    x = ((float)qx + 0.5f) * (1.0f/256.0f) * 102.4f - 51.2f;
    y = ((float)qy + 0.5f) * (1.0f/256.0f) * 102.4f - 51.2f;
}

// ---------- kernel 1: per-256q-subchunk visible-pillar counts ----------
// grid (64, 24), 256 threads. Each wave owns 256 consecutive q -> one count.
__global__ void __launch_bounds__(256)
k_count(const float* __restrict__ ego2img, int* __restrict__ chunkCounts)
{
    int chunk = blockIdx.x, row = blockIdx.y;
    float m[12]; load_mat(ego2img, row, m);
    int t = threadIdx.x;
    int lane = t & 63;
    int q0 = chunk * 1024 + t * 4;
    int cnt = 0;
    #pragma unroll
    for (int i = 0; i < 4; ++i) {
        int q = q0 + i;
        float x, y; bev_xy(q & 255, q >> 8, x, y);
        bool va = false;
        #pragma unroll
        for (int d = 0; d < 4; ++d) {
            float u, v;
            va |= proj_point(m, x, y, zval(d), u, v);
        }
        unsigned long long bal = __ballot(va);
        if (lane == 0) cnt += __popcll(bal);
    }
    if (lane == 0)
        chunkCounts[row * 256 + chunk * 4 + (t >> 6)] = cnt;
}

// ---------- kernel 2: wave-per-camera fused pack + restore + counts ----------
// grid (256, NB), 384 threads = 6 waves. Block = one BEV row (qy = blockIdx.x)
// of one batch; wave w owns camera w. The per-chunk prefix scan, ranking, and
// all pack/tail stores are wave-local -> ZERO barriers in the pack phase (no
// per-camera vmcnt(0) store drains). One __syncthreads publishes rank-or-(-1)
// per (cam,q) in LDS; then wave o computes restore plane o branchlessly and
// wave 0 emits counts.
__global__ void __launch_bounds__(384)
k_fused(const float* __restrict__ ego2img, const int* __restrict__ chunkCounts,
        float* __restrict__ out)
{
    int chunk = blockIdx.x, b = blockIdx.y;
    int t = threadIdx.x;
    int lane = t & 63;
    int c = t >> 6;                         // wave id == camera id, 0..5
    unsigned long long lt = (1ull << lane) - 1ull;

    __shared__ int lrank[NCAM][256];        // packed rank or -1, 6 KB

    int row = __builtin_amdgcn_readfirstlane(b * NCAM + c);

    // wave-local exclusive prefix over this camera's 256 subchunk counts
    const int* p = chunkCounts + row * 256;
    int4 v4 = ((const int4*)p)[lane];       // 4 consecutive counts per lane
    int s = v4.x + v4.y + v4.z + v4.w;
    int incl = s;
    #pragma unroll
    for (int off = 1; off < 64; off <<= 1) {
        int nn = __shfl_up(incl, off, 64);
        if (lane >= off) incl += nn;
    }
    int k = chunk & 3;
    int bb = incl - s + ((k > 0) ? v4.x : 0)
                      + ((k > 1) ? v4.y : 0)
                      + ((k > 2) ? v4.z : 0);
    int base  = __shfl(bb,   chunk >> 2, 64);   // exclusive base at my chunk
    int total = __shfl(incl, 63,        64);    // camera total visible

    float m[12]; load_mat(ego2img, row, m);

    float2* qgrid  = (float2*)(out + OFF_QGRID)  + (size_t)row * MAXLEN_;
    float4* refpF4 = (float4*)(out + OFF_REFPTS) + (size_t)row * (MAXLEN_ * 2);

    int qy = chunk;

    // pack phase: 4 chunks of 64 q, no barriers, stores free-flowing
    #pragma unroll
    for (int i = 0; i < 4; ++i) {
        int qx = i * 64 + lane;
        float x, y; bev_xy(qx, qy, x, y);
        float uv[8];
        bool vis = false;
        #pragma unroll
        for (int d = 0; d < 4; ++d) {
            float u, v;
            bool vi = proj_point(m, x, y, zval(d), u, v);
            uv[2*d]   = clip21(u);
            uv[2*d+1] = clip21(v);
            vis |= vi;
        }
        unsigned long long bal = __ballot(vis);
        int r = base + __popcll(bal & lt);
        if (vis) {
            float2 g;
            g.x = ((float)qx / 255.0f) * 2.0f - 1.0f;
            g.y = ((float)qy / 255.0f) * 2.0f - 1.0f;
            qgrid[r] = g;
            refpF4[2*r]     = make_float4(uv[0], uv[1], uv[2], uv[3]);
            refpF4[2*r + 1] = make_float4(uv[4], uv[5], uv[6], uv[7]);
        }
        lrank[c][qx] = vis ? r : -1;
        base += __popcll(bal);
    }

    // tail fill for this camera: this block owns slots [256*chunk, 256*chunk+256)
    int s0 = max(total, chunk << 8);
    int n  = ((chunk + 1) << 8) - s0;
    if (n > 0) {
        for (int j = lane; j < n; j += 64)
            qgrid[s0 + j] = make_float2(-1.5f, -1.5f);
        float4 z4 = make_float4(0.f, 0.f, 0.f, 0.f);
        for (int j = lane; j < 2 * n; j += 64)
            refpF4[2*s0 + j] = z4;
    }

    __syncthreads();   // the ONLY block barrier: lrank ready

    // restore plane o == c for this row; wave 0 also writes counts
    float2* rest = (float2*)(out + OFF_RESTORE) + (size_t)b * NCAM * NQ;
    int o = c;
    #pragma unroll
    for (int i = 0; i < 4; ++i) {
        int qx = i * 64 + lane;
        float2 val = make_float2(-1.5f, -1.5f);
        int cnt = 0;
        #pragma unroll
        for (int cc = 0; cc < NCAM; ++cc) {
            int r = lrank[cc][qx];
            bool v = (r >= 0);
            if (v && (cnt == o)) {
                val.x = ((float)(r & 255) / 255.0f) * 2.0f - 1.0f;
                val.y = ((float)(cc * 256 + (r >> 8)) / 1535.0f) * 2.0f - 1.0f;
            }
            cnt += v;
        }
        rest[(o * 256 + qy) * 256 + qx] = val;
        if (c == 0)
            out[OFF_COUNTS + (size_t)b * NQ + qy * 256 + qx] =
                1.0f / fmaxf((float)cnt, 1.0f);
    }
}

extern "C" void kernel_launch(void* const* d_in, const int* in_sizes, int n_in,
                              void* d_out, int out_size, void* d_ws, size_t ws_size,
                              hipStream_t stream)
{
    const float* ego2img = (const float*)d_in[0];
    float* out = (float*)d_out;
    int* chunkCounts = (int*)d_ws;   // 24*256 ints = 24.6 KB

    k_count<<<dim3(64, NROWS), 256, 0, stream>>>(ego2img, chunkCounts);
    k_fused<<<dim3(256, NB),   384, 0, stream>>>(ego2img, chunkCounts, out);
}